// Round 3
// baseline (1445.691 us; speedup 1.0000x reference)
//
#include <hip/hip_runtime.h>

#define N_NODES 30000
#define N_EDGES 240000
#define EMB     300
#define NPAD    30080   // 235 * 128
#define KP1     320     // padded EMB (hi-plane K of gemm1)
#define K1D     640     // 2*KP1: hi+lo planes (gemm1 K)
#define NP1     640     // padded 2*EMB (gemm1 out cols)
#define K2D     1280    // 2*NP1: hi+lo planes (gemm2 K)
#define NP2     384     // gemm2 padded col count (compute)
#define HS2     304     // h2 row stride fp32 (stores masked to col<HS2)
#define HSF     304     // h row stride in fp32 elements
#define LAYERS  5

typedef __attribute__((ext_vector_type(8))) short short8;
typedef __attribute__((ext_vector_type(4))) float floatx4;

__device__ __forceinline__ unsigned short f2bf(float f) {
  union { float f; unsigned int u; } v; v.f = f;
  unsigned int u = v.u;
  unsigned int r = (u + 0x7fffu + ((u >> 16) & 1u)) >> 16;
  return (unsigned short)r;
}
__device__ __forceinline__ float bf2f(unsigned int u) {
  union { unsigned int u; float f; } v; v.u = u << 16; return v.f;
}

// ---------------- weight conversion / transpose (K-duplicated for split-A) ----------------
__global__ void conv_w1t_kernel(const float* __restrict__ W1, unsigned short* __restrict__ w1t) {
  int idx = blockIdx.x * 256 + threadIdx.x;
  if (idx >= LAYERS * NP1 * K1D) return;
  int l = idx / (NP1 * K1D);
  int rem = idx % (NP1 * K1D);
  int n = rem / K1D, k = rem % K1D;
  int k2 = (k >= KP1) ? k - KP1 : k;   // duplicate along K for lo-plane
  float v = (n < 2 * EMB && k2 < EMB) ? W1[(size_t)l * EMB * 2 * EMB + (size_t)k2 * 2 * EMB + n] : 0.f;
  w1t[idx] = f2bf(v);
}
__global__ void conv_w2t_kernel(const float* __restrict__ W2, unsigned short* __restrict__ w2t) {
  int idx = blockIdx.x * 256 + threadIdx.x;
  if (idx >= LAYERS * NP2 * K2D) return;
  int l = idx / (NP2 * K2D);
  int rem = idx % (NP2 * K2D);
  int n = rem / K2D, k = rem % K2D;
  int k2 = (k >= NP1) ? k - NP1 : k;
  float v = (n < EMB && k2 < 2 * EMB) ? W2[(size_t)l * 2 * EMB * EMB + (size_t)k2 * EMB + n] : 0.f;
  w2t[idx] = f2bf(v);
}
__global__ void conv_bias_kernel(const float* __restrict__ b, float* __restrict__ bp,
                                 int n_real, int n_pad) {
  int idx = blockIdx.x * 256 + threadIdx.x;
  if (idx >= LAYERS * n_pad) return;
  int l = idx / n_pad, j = idx % n_pad;
  bp[idx] = (j < n_real) ? b[l * n_real + j] : 0.f;
}

// ---------------- initial embedding (fp32 h) ----------------
__global__ __launch_bounds__(256)
void embed_kernel(const int* __restrict__ x, const float* __restrict__ emb1,
                  const float* __restrict__ emb2, float* __restrict__ h) {
  int node = blockIdx.x;
  int t0 = x[node * 2], t1 = x[node * 2 + 1];
  for (int c = threadIdx.x; c < EMB; c += 256)
    h[(size_t)node * HSF + c] = emb1[t0 * EMB + c] + emb2[t1 * EMB + c];
}

// ---------------- CSR build ----------------
__global__ void count_kernel(const int* __restrict__ ei, int* __restrict__ deg) {
  int e = blockIdx.x * 256 + threadIdx.x;
  if (e < N_EDGES) atomicAdd(&deg[ei[N_EDGES + e]], 1);
}

__global__ __launch_bounds__(1024)
void scan_kernel(const int* __restrict__ deg, int* __restrict__ row_ptr) {
  __shared__ int smem[1024];
  __shared__ int s_running;
  int tid = threadIdx.x;
  if (tid == 0) s_running = 0;
  __syncthreads();
  for (int base = 0; base < N_NODES; base += 1024) {
    int i = base + tid;
    int v = (i < N_NODES) ? deg[i] : 0;
    smem[tid] = v;
    __syncthreads();
    for (int off = 1; off < 1024; off <<= 1) {
      int t = (tid >= off) ? smem[tid - off] : 0;
      __syncthreads();
      smem[tid] += t;
      __syncthreads();
    }
    int incl = smem[tid];
    int run = s_running;
    if (i < N_NODES) row_ptr[i] = run + incl - v;
    __syncthreads();
    if (tid == 1023) s_running = run + smem[1023];
    __syncthreads();
  }
  if (tid == 0) row_ptr[N_NODES] = s_running;
}

__global__ void copy_kernel(const int* __restrict__ src, int* __restrict__ dst) {
  int i = blockIdx.x * 256 + threadIdx.x;
  if (i < N_NODES) dst[i] = src[i];
}

__global__ void fill_kernel(const int* __restrict__ ei, const int* __restrict__ ea,
                            int* __restrict__ cursor, int* __restrict__ ebuf) {
  int e = blockIdx.x * 256 + threadIdx.x;
  if (e >= N_EDGES) return;
  int d = ei[N_EDGES + e];
  int pos = atomicAdd(&cursor[d], 1);
  ebuf[pos] = ei[e] * 32 + (ea[2 * e] * 3 + ea[2 * e + 1]);  // src*32 + combo
}

// ---------------- aggregation: fp32 gather-sum, split hi/lo bf16 output ----------------
// one wave per node; lane covers float2 slots {lane, lane+64, lane+128(<150)}
__global__ __launch_bounds__(256)
void aggregate_kernel(const float* __restrict__ h,
                      const int* __restrict__ row_ptr,
                      const int* __restrict__ ebuf,
                      const float* __restrict__ e1,   // [6,300] this layer
                      const float* __restrict__ e2,   // [3,300] this layer
                      unsigned short* __restrict__ agg) {
  __shared__ float2 combo[18][150];
  int tid = threadIdx.x;
  for (int idx = tid; idx < 18 * 150; idx += 256) {
    int t = idx / 150, p = idx % 150;
    int a0 = t / 3, a1 = t % 3;
    float2 c;
    c.x = e1[a0 * EMB + 2 * p]     + e2[a1 * EMB + 2 * p];
    c.y = e1[a0 * EMB + 2 * p + 1] + e2[a1 * EMB + 2 * p + 1];
    combo[t][p] = c;
  }
  __syncthreads();
  int wave = tid >> 6, lane = tid & 63;
  int node = blockIdx.x * 4 + wave;
  float a0x = 0.f, a0y = 0.f, a1x = 0.f, a1y = 0.f, a2x = 0.f, a2y = 0.f;
  int p2 = lane + 128;
  bool has2 = (p2 < 150);
  if (node < N_NODES) {
    int ebeg = row_ptr[node], eend = row_ptr[node + 1];
    for (int e = ebeg; e <= eend; ++e) {   // e == eend -> self loop
      int s, t;
      if (e < eend) { int v = ebuf[e]; s = v >> 5; t = v & 31; }
      else          { s = node;        t = 4 * 3 + 0; }
      const float2* hp = (const float2*)(h + (size_t)s * HSF);
      float2 u0 = hp[lane];
      float2 u1 = hp[lane + 64];
      float2 c0 = combo[t][lane];
      float2 c1 = combo[t][lane + 64];
      a0x += u0.x + c0.x;  a0y += u0.y + c0.y;
      a1x += u1.x + c1.x;  a1y += u1.y + c1.y;
      if (has2) {
        float2 u2 = hp[p2];
        float2 c2 = combo[t][p2];
        a2x += u2.x + c2.x;  a2y += u2.y + c2.y;
      }
    }
  }
  // write hi plane (uints 0..159) and lo plane (uints 160..319)
  unsigned int* op = (unsigned int*)(agg + (size_t)node * K1D);
  unsigned short hx, hy, lx, ly;
#define WR(ui, X, Y) \
  hx = f2bf(X); hy = f2bf(Y); \
  op[(ui)] = (unsigned)hx | ((unsigned)hy << 16); \
  lx = f2bf((X) - bf2f(hx)); ly = f2bf((Y) - bf2f(hy)); \
  op[(ui) + KP1 / 2] = (unsigned)lx | ((unsigned)ly << 16);
  WR(lane, a0x, a0y)
  WR(lane + 64, a1x, a1y)
  if (p2 < 160) {
    if (has2) { WR(p2, a2x, a2y) }
    else { op[p2] = 0u; op[p2 + KP1 / 2] = 0u; }   // zero K-pad cols (both planes)
  }
#undef WR
}

// ---------------- bf16 MFMA GEMM: C = act(A @ B^T + bias) ----------------
// A: [Mpad, lda] bf16 row-major (hi|lo planes along K). Bt: [Npad, ldb] bf16, K-duplicated.
// 128x128 tile, 4 waves of 64x64, K-step 32 via mfma_f32_16x16x32_bf16.
// OUT_MODE: 0 = fp32 store (cols < col_lim); 1 = split hi/lo bf16 store (lo at col+lo_off).
template<int RELU, int OUT_MODE>
__global__ __launch_bounds__(256, 2)
void gemm_kernel(const unsigned short* __restrict__ A, int lda,
                 const unsigned short* __restrict__ Bt, int ldb,
                 const float* __restrict__ bias,
                 void* __restrict__ C, int ldc, int K, int lo_off, int col_lim) {
  __shared__ unsigned short As[128 * 40];   // row stride 40 (+8 pad)
  __shared__ unsigned short Bs[128 * 40];
  int tid = threadIdx.x;
  int wave = tid >> 6, lane = tid & 63;
  int wm = wave >> 1, wn = wave & 1;
  int row0 = blockIdx.x * 128, col0 = blockIdx.y * 128;
  floatx4 zero4 = {0.f, 0.f, 0.f, 0.f};
  floatx4 acc[4][4];
#pragma unroll
  for (int i = 0; i < 4; ++i)
#pragma unroll
    for (int j = 0; j < 4; ++j) acc[i][j] = zero4;

  for (int kc = 0; kc < K; kc += 32) {
#pragma unroll
    for (int it = 0; it < 2; ++it) {
      int idx = tid + it * 256;     // 0..511
      int r = idx >> 2;             // row 0..127
      int ck = (idx & 3) << 3;      // bf16 col offset 0,8,16,24
      *(uint4*)(&As[r * 40 + ck]) = *(const uint4*)(&A[(size_t)(row0 + r) * lda + kc + ck]);
      *(uint4*)(&Bs[r * 40 + ck]) = *(const uint4*)(&Bt[(size_t)(col0 + r) * ldb + kc + ck]);
    }
    __syncthreads();
    short8 af[4], bfr[4];
#pragma unroll
    for (int mi = 0; mi < 4; ++mi)
      af[mi] = *(const short8*)&As[(wm * 64 + mi * 16 + (lane & 15)) * 40 + (lane >> 4) * 8];
#pragma unroll
    for (int ni = 0; ni < 4; ++ni)
      bfr[ni] = *(const short8*)&Bs[(wn * 64 + ni * 16 + (lane & 15)) * 40 + (lane >> 4) * 8];
#pragma unroll
    for (int mi = 0; mi < 4; ++mi)
#pragma unroll
      for (int ni = 0; ni < 4; ++ni)
        acc[mi][ni] = __builtin_amdgcn_mfma_f32_16x16x32_bf16(af[mi], bfr[ni], acc[mi][ni], 0, 0, 0);
    __syncthreads();
  }
  // epilogue: C/D layout col=lane&15, row=quad*4+reg
#pragma unroll
  for (int mi = 0; mi < 4; ++mi) {
#pragma unroll
    for (int ni = 0; ni < 4; ++ni) {
      int col = col0 + wn * 64 + ni * 16 + (lane & 15);
      float bv = bias[col];
#pragma unroll
      for (int r = 0; r < 4; ++r) {
        int row = row0 + wm * 64 + mi * 16 + (lane >> 4) * 4 + r;
        float v = acc[mi][ni][r] + bv;
        if (RELU) v = fmaxf(v, 0.f);
        if (OUT_MODE == 1) {
          unsigned short hi = f2bf(v);
          unsigned short lo = f2bf(v - bf2f(hi));
          ((unsigned short*)C)[(size_t)row * ldc + col] = hi;
          ((unsigned short*)C)[(size_t)row * ldc + col + lo_off] = lo;
        } else {
          if (col < col_lim)
            ((float*)C)[(size_t)row * ldc + col] = v;
        }
      }
    }
  }
}

// ---------------- batchnorm stats (sum, sumsq per channel) ----------------
__global__ __launch_bounds__(256)
void stats_kernel(const float* __restrict__ h2, float* __restrict__ stats) {
  int tid = threadIdx.x;
  int base = blockIdx.x * 128;
  float s0 = 0.f, q0 = 0.f, s1 = 0.f, q1 = 0.f;
  int c1 = tid + 256;
  for (int r = 0; r < 128; ++r) {
    int row = base + r;
    if (row >= N_NODES) break;
    const float* p = h2 + (size_t)row * HS2;
    float v = p[tid];
    s0 += v; q0 += v * v;
    if (c1 < EMB) { float w = p[c1]; s1 += w; q1 += w * w; }
  }
  atomicAdd(&stats[tid], s0);
  atomicAdd(&stats[EMB + tid], q0);
  if (c1 < EMB) { atomicAdd(&stats[c1], s1); atomicAdd(&stats[EMB + c1], q1); }
}

// ---------------- batchnorm apply (+relu), fp32 h out ----------------
__global__ __launch_bounds__(256)
void bn_kernel(const float* __restrict__ h2, const float* __restrict__ stats,
               const float* __restrict__ gamma, const float* __restrict__ beta,
               float* __restrict__ hout, float* __restrict__ fout, int relu) {
  int node = blockIdx.x;
  const float invN = 1.0f / (float)N_NODES;
  for (int c = threadIdx.x; c < EMB; c += 256) {
    float mean = stats[c] * invN;
    float var = stats[EMB + c] * invN - mean * mean;
    float scale = gamma[c] * rsqrtf(var + 1e-5f);
    float shift = beta[c] - mean * scale;
    float v = h2[(size_t)node * HS2 + c] * scale + shift;
    if (relu) v = fmaxf(v, 0.f);
    if (hout) hout[(size_t)node * HSF + c] = v;
    else      fout[(size_t)node * EMB + c] = v;
  }
}

extern "C" void kernel_launch(void* const* d_in, const int* in_sizes, int n_in,
                              void* d_out, int out_size, void* d_ws, size_t ws_size,
                              hipStream_t stream) {
  const int*   x      = (const int*)d_in[0];
  const int*   ei     = (const int*)d_in[1];
  const int*   ea     = (const int*)d_in[2];
  const float* x_emb1 = (const float*)d_in[3];
  const float* x_emb2 = (const float*)d_in[4];
  const float* edge1  = (const float*)d_in[5];
  const float* edge2  = (const float*)d_in[6];
  const float* W1     = (const float*)d_in[7];
  const float* b1     = (const float*)d_in[8];
  const float* W2     = (const float*)d_in[9];
  const float* b2     = (const float*)d_in[10];
  const float* gamma  = (const float*)d_in[11];
  const float* beta   = (const float*)d_in[12];
  float* out = (float*)d_out;

  char* ws = (char*)d_ws;
  size_t off = 0;
  auto nxt = [&](size_t bytes) {
    void* p = ws + off;
    off += (bytes + 255) & ~(size_t)255;
    return p;
  };
  // Region R: tbuf (bf16 [NPAD][K2D], live gemm1->gemm2) aliases hbuf
  // (fp32 [N_NODES][HSF], read only by aggregate, rewritten by bn).
  size_t tbuf_bytes = (size_t)NPAD * K2D * 2;        // 77.0 MB
  size_t hbuf_bytes = (size_t)N_NODES * HSF * 4;     // 36.5 MB
  char* R = (char*)nxt(tbuf_bytes > hbuf_bytes ? tbuf_bytes : hbuf_bytes);
  float*          hbuf = (float*)R;
  unsigned short* tbuf = (unsigned short*)R;
  // Region S: aggb (bf16 [NPAD][K1D], live aggregate->gemm1) aliases h2
  // (fp32 [NPAD][HS2], live gemm2->bn).
  size_t agg_bytes = (size_t)NPAD * K1D * 2;         // 38.5 MB
  size_t h2_bytes  = (size_t)NPAD * HS2 * 4;         // 36.6 MB
  char* S = (char*)nxt(agg_bytes > h2_bytes ? agg_bytes : h2_bytes);
  unsigned short* aggb = (unsigned short*)S;
  float*          h2   = (float*)S;
  unsigned short* w1t  = (unsigned short*)nxt((size_t)LAYERS * NP1 * K1D * 2);
  unsigned short* w2t  = (unsigned short*)nxt((size_t)LAYERS * NP2 * K2D * 2);
  float*          b1p  = (float*)nxt((size_t)LAYERS * NP1 * 4);
  float*          b2p  = (float*)nxt((size_t)LAYERS * NP2 * 4);
  float*          stat = (float*)nxt((size_t)LAYERS * 2 * EMB * 4);
  int*            deg  = (int*)nxt((size_t)N_NODES * 4);
  int*            rptr = (int*)nxt((size_t)(N_NODES + 1) * 4);
  int*            curs = (int*)nxt((size_t)N_NODES * 4);
  int*            ebuf = (int*)nxt((size_t)N_EDGES * 4);
  // total ~125.9 MB (= 120.0 MiB)

  hipMemsetAsync(deg, 0, (size_t)N_NODES * 4, stream);
  hipMemsetAsync(stat, 0, (size_t)LAYERS * 2 * EMB * 4, stream);

  conv_w1t_kernel<<<(LAYERS * NP1 * K1D + 255) / 256, 256, 0, stream>>>(W1, w1t);
  conv_w2t_kernel<<<(LAYERS * NP2 * K2D + 255) / 256, 256, 0, stream>>>(W2, w2t);
  conv_bias_kernel<<<(LAYERS * NP1 + 255) / 256, 256, 0, stream>>>(b1, b1p, 2 * EMB, NP1);
  conv_bias_kernel<<<(LAYERS * NP2 + 255) / 256, 256, 0, stream>>>(b2, b2p, EMB, NP2);

  embed_kernel<<<N_NODES, 256, 0, stream>>>(x, x_emb1, x_emb2, hbuf);

  count_kernel<<<(N_EDGES + 255) / 256, 256, 0, stream>>>(ei, deg);
  scan_kernel<<<1, 1024, 0, stream>>>(deg, rptr);
  copy_kernel<<<(N_NODES + 255) / 256, 256, 0, stream>>>(rptr, curs);
  fill_kernel<<<(N_EDGES + 255) / 256, 256, 0, stream>>>(ei, ea, curs, ebuf);

  for (int l = 0; l < LAYERS; ++l) {
    aggregate_kernel<<<NPAD / 4, 256, 0, stream>>>(
        hbuf, rptr, ebuf, edge1 + (size_t)l * 6 * EMB, edge2 + (size_t)l * 3 * EMB, aggb);
    gemm_kernel<1, 1><<<dim3(NPAD / 128, NP1 / 128), 256, 0, stream>>>(
        aggb, K1D, w1t + (size_t)l * NP1 * K1D, K1D, b1p + l * NP1, tbuf, K2D, K1D, NP1, NP1);
    gemm_kernel<0, 0><<<dim3(NPAD / 128, NP2 / 128), 256, 0, stream>>>(
        tbuf, K2D, w2t + (size_t)l * NP2 * K2D, K2D, b2p + l * NP2, h2, HS2, K2D, 0, HS2);
    stats_kernel<<<NPAD / 128, 256, 0, stream>>>(h2, stat + l * 2 * EMB);
    bn_kernel<<<N_NODES, 256, 0, stream>>>(
        h2, stat + l * 2 * EMB, gamma + l * EMB, beta + l * EMB,
        (l < LAYERS - 1) ? hbuf : (float*)nullptr,
        (l < LAYERS - 1) ? (float*)nullptr : out,
        (l < LAYERS - 1) ? 1 : 0);
  }
}

// Round 4
// 1344.857 us; speedup vs baseline: 1.0750x; 1.0750x over previous
//
#include <hip/hip_runtime.h>
#include <hip/hip_fp16.h>

#define N_NODES 30000
#define N_EDGES 240000
#define EMB     300
#define NPAD    30080   // 235 * 128
#define KP1     320     // padded EMB (hi-plane K of gemm1)
#define K1D     640     // 2*KP1: hi+lo planes (gemm1 K)
#define NP1     640     // padded 2*EMB (gemm1 out cols)
#define K2D     1280    // 2*NP1: hi+lo planes (gemm2 K)
#define NP2     384     // gemm2 padded col count (compute)
#define HS2     304     // h2 row stride fp32 (stores masked to col<HS2)
#define HSH     304     // h row stride in fp16 elements
#define LAYERS  5

typedef __attribute__((ext_vector_type(8))) short short8;
typedef __attribute__((ext_vector_type(4))) float floatx4;

__device__ __forceinline__ unsigned short f2bf(float f) {
  union { float f; unsigned int u; } v; v.f = f;
  unsigned int u = v.u;
  unsigned int r = (u + 0x7fffu + ((u >> 16) & 1u)) >> 16;
  return (unsigned short)r;
}
__device__ __forceinline__ float bf2f(unsigned int u) {
  union { unsigned int u; float f; } v; v.u = u << 16; return v.f;
}
// async 16B global->LDS (per-lane gptr, LDS dest = wave-uniform base + lane*16)
__device__ __forceinline__ void gload16(const void* g, void* l) {
  __builtin_amdgcn_global_load_lds(
      (const __attribute__((address_space(1))) unsigned int*)g,
      (__attribute__((address_space(3))) unsigned int*)l, 16, 0, 0);
}

// ---------------- weight conversion / transpose (K-duplicated for split-A) ----------------
__global__ void conv_w1t_kernel(const float* __restrict__ W1, unsigned short* __restrict__ w1t) {
  int idx = blockIdx.x * 256 + threadIdx.x;
  if (idx >= LAYERS * NP1 * K1D) return;
  int l = idx / (NP1 * K1D);
  int rem = idx % (NP1 * K1D);
  int n = rem / K1D, k = rem % K1D;
  int k2 = (k >= KP1) ? k - KP1 : k;   // duplicate along K for lo-plane
  float v = (n < 2 * EMB && k2 < EMB) ? W1[(size_t)l * EMB * 2 * EMB + (size_t)k2 * 2 * EMB + n] : 0.f;
  w1t[idx] = f2bf(v);
}
__global__ void conv_w2t_kernel(const float* __restrict__ W2, unsigned short* __restrict__ w2t) {
  int idx = blockIdx.x * 256 + threadIdx.x;
  if (idx >= LAYERS * NP2 * K2D) return;
  int l = idx / (NP2 * K2D);
  int rem = idx % (NP2 * K2D);
  int n = rem / K2D, k = rem % K2D;
  int k2 = (k >= NP1) ? k - NP1 : k;
  float v = (n < EMB && k2 < 2 * EMB) ? W2[(size_t)l * 2 * EMB * EMB + (size_t)k2 * EMB + n] : 0.f;
  w2t[idx] = f2bf(v);
}
__global__ void conv_bias_kernel(const float* __restrict__ b, float* __restrict__ bp,
                                 int n_real, int n_pad) {
  int idx = blockIdx.x * 256 + threadIdx.x;
  if (idx >= LAYERS * n_pad) return;
  int l = idx / n_pad, j = idx % n_pad;
  bp[idx] = (j < n_real) ? b[l * n_real + j] : 0.f;
}

// ---------------- initial embedding (fp16 h) ----------------
__global__ __launch_bounds__(256)
void embed_kernel(const int* __restrict__ x, const float* __restrict__ emb1,
                  const float* __restrict__ emb2, __half* __restrict__ h) {
  int node = blockIdx.x;
  int t0 = x[node * 2], t1 = x[node * 2 + 1];
  for (int c = threadIdx.x; c < EMB; c += 256)
    h[(size_t)node * HSH + c] = __float2half(emb1[t0 * EMB + c] + emb2[t1 * EMB + c]);
}

// ---------------- CSR build ----------------
__global__ void count_kernel(const int* __restrict__ ei, int* __restrict__ deg) {
  int e = blockIdx.x * 256 + threadIdx.x;
  if (e < N_EDGES) atomicAdd(&deg[ei[N_EDGES + e]], 1);
}

__global__ __launch_bounds__(1024)
void scan_kernel(const int* __restrict__ deg, int* __restrict__ row_ptr) {
  __shared__ int smem[1024];
  __shared__ int s_running;
  int tid = threadIdx.x;
  if (tid == 0) s_running = 0;
  __syncthreads();
  for (int base = 0; base < N_NODES; base += 1024) {
    int i = base + tid;
    int v = (i < N_NODES) ? deg[i] : 0;
    smem[tid] = v;
    __syncthreads();
    for (int off = 1; off < 1024; off <<= 1) {
      int t = (tid >= off) ? smem[tid - off] : 0;
      __syncthreads();
      smem[tid] += t;
      __syncthreads();
    }
    int incl = smem[tid];
    int run = s_running;
    if (i < N_NODES) row_ptr[i] = run + incl - v;
    __syncthreads();
    if (tid == 1023) s_running = run + smem[1023];
    __syncthreads();
  }
  if (tid == 0) row_ptr[N_NODES] = s_running;
}

__global__ void copy_kernel(const int* __restrict__ src, int* __restrict__ dst) {
  int i = blockIdx.x * 256 + threadIdx.x;
  if (i < N_NODES) dst[i] = src[i];
}

__global__ void fill_kernel(const int* __restrict__ ei, const int* __restrict__ ea,
                            int* __restrict__ cursor, int* __restrict__ ebuf) {
  int e = blockIdx.x * 256 + threadIdx.x;
  if (e >= N_EDGES) return;
  int d = ei[N_EDGES + e];
  int pos = atomicAdd(&cursor[d], 1);
  ebuf[pos] = ei[e] * 32 + (ea[2 * e] * 3 + ea[2 * e + 1]);  // src*32 + combo
}

// ---------------- aggregation: fp16 gather-sum, split hi/lo bf16 output ----------------
// one wave per node; lane covers half2 slots {lane, lane+64, lane+128(<150)}
__global__ __launch_bounds__(256)
void aggregate_kernel(const __half* __restrict__ h,
                      const int* __restrict__ row_ptr,
                      const int* __restrict__ ebuf,
                      const float* __restrict__ e1,   // [6,300] this layer
                      const float* __restrict__ e2,   // [3,300] this layer
                      unsigned short* __restrict__ agg) {
  __shared__ float2 combo[18][150];
  int tid = threadIdx.x;
  for (int idx = tid; idx < 18 * 150; idx += 256) {
    int t = idx / 150, p = idx % 150;
    int a0 = t / 3, a1 = t % 3;
    float2 c;
    c.x = e1[a0 * EMB + 2 * p]     + e2[a1 * EMB + 2 * p];
    c.y = e1[a0 * EMB + 2 * p + 1] + e2[a1 * EMB + 2 * p + 1];
    combo[t][p] = c;
  }
  __syncthreads();
  int wave = tid >> 6, lane = tid & 63;
  int node = blockIdx.x * 4 + wave;
  float a0x = 0.f, a0y = 0.f, a1x = 0.f, a1y = 0.f, a2x = 0.f, a2y = 0.f;
  int p2 = lane + 128;
  bool has2 = (p2 < 150);
  if (node < N_NODES) {
    int ebeg = row_ptr[node], eend = row_ptr[node + 1];
    for (int e = ebeg; e <= eend; ++e) {   // e == eend -> self loop
      int s, t;
      if (e < eend) { int v = ebuf[e]; s = v >> 5; t = v & 31; }
      else          { s = node;        t = 4 * 3 + 0; }
      const __half2* hp = (const __half2*)(h + (size_t)s * HSH);
      float2 u0 = __half22float2(hp[lane]);
      float2 u1 = __half22float2(hp[lane + 64]);
      float2 c0 = combo[t][lane];
      float2 c1 = combo[t][lane + 64];
      a0x += u0.x + c0.x;  a0y += u0.y + c0.y;
      a1x += u1.x + c1.x;  a1y += u1.y + c1.y;
      if (has2) {
        float2 u2 = __half22float2(hp[p2]);
        float2 c2 = combo[t][p2];
        a2x += u2.x + c2.x;  a2y += u2.y + c2.y;
      }
    }
  }
  // write hi plane (uints 0..159) and lo plane (uints 160..319)
  unsigned int* op = (unsigned int*)(agg + (size_t)node * K1D);
  unsigned short hx, hy, lx, ly;
#define WR(ui, X, Y) \
  hx = f2bf(X); hy = f2bf(Y); \
  op[(ui)] = (unsigned)hx | ((unsigned)hy << 16); \
  lx = f2bf((X) - bf2f(hx)); ly = f2bf((Y) - bf2f(hy)); \
  op[(ui) + KP1 / 2] = (unsigned)lx | ((unsigned)ly << 16);
  WR(lane, a0x, a0y)
  WR(lane + 64, a1x, a1y)
  if (p2 < 160) {
    if (has2) { WR(p2, a2x, a2y) }
    else { op[p2] = 0u; op[p2 + KP1 / 2] = 0u; }   // zero K-pad cols (both planes)
  }
#undef WR
}

// ---------------- bf16 MFMA GEMM: C = act(A @ B^T + bias) ----------------
// m97-style: global_load_lds width=16 staging, unpadded LDS (stride 32 bf16).
// A: [Mpad, lda] bf16 row-major (hi|lo planes along K). Bt: [Npad, ldb] bf16, K-duplicated.
// 128x128 tile, 4 waves of 64x64, K-step 32 via mfma_f32_16x16x32_bf16.
// OUT_MODE: 0 = fp32 store (cols < col_lim); 1 = split hi/lo bf16 store (lo at col+lo_off).
template<int RELU, int OUT_MODE>
__global__ __launch_bounds__(256, 2)
void gemm_kernel(const unsigned short* __restrict__ A, int lda,
                 const unsigned short* __restrict__ Bt, int ldb,
                 const float* __restrict__ bias,
                 void* __restrict__ C, int ldc, int K, int lo_off, int col_lim) {
  __shared__ unsigned short As[128 * 32];   // unpadded: row = 64 B, lane-order contiguous
  __shared__ unsigned short Bs[128 * 32];
  int tid = threadIdx.x;
  int wave = tid >> 6, lane = tid & 63;
  int wm = wave >> 1, wn = wave & 1;
  int row0 = blockIdx.x * 128, col0 = blockIdx.y * 128;
  // staging: thread t covers (row sr, 16B chunk sc) and (row 64+sr, chunk sc);
  // LDS offset = tid*16 B (wave-uniform base + lane*16 — required by global_load_lds)
  int sr = tid >> 2, sc = (tid & 3) * 8;           // sc in bf16 elems
  const unsigned short* ga0 = A + (size_t)(row0 + sr) * lda + sc;
  const unsigned short* ga1 = A + (size_t)(row0 + 64 + sr) * lda + sc;
  const unsigned short* gb0 = Bt + (size_t)(col0 + sr) * ldb + sc;
  const unsigned short* gb1 = Bt + (size_t)(col0 + 64 + sr) * ldb + sc;
  unsigned short* la0 = &As[sr * 32 + sc];          // = tid*8 shorts
  unsigned short* la1 = &As[(64 + sr) * 32 + sc];
  unsigned short* lb0 = &Bs[sr * 32 + sc];
  unsigned short* lb1 = &Bs[(64 + sr) * 32 + sc];

  floatx4 zero4 = {0.f, 0.f, 0.f, 0.f};
  floatx4 acc[4][4];
#pragma unroll
  for (int i = 0; i < 4; ++i)
#pragma unroll
    for (int j = 0; j < 4; ++j) acc[i][j] = zero4;

  for (int kc = 0; kc < K; kc += 32) {
    gload16(ga0 + kc, la0);
    gload16(ga1 + kc, la1);
    gload16(gb0 + kc, lb0);
    gload16(gb1 + kc, lb1);
    __syncthreads();   // drains vmcnt (global_load_lds) + lgkm before barrier
    short8 af[4], bfr[4];
#pragma unroll
    for (int mi = 0; mi < 4; ++mi)
      af[mi] = *(const short8*)&As[(wm * 64 + mi * 16 + (lane & 15)) * 32 + (lane >> 4) * 8];
#pragma unroll
    for (int ni = 0; ni < 4; ++ni)
      bfr[ni] = *(const short8*)&Bs[(wn * 64 + ni * 16 + (lane & 15)) * 32 + (lane >> 4) * 8];
#pragma unroll
    for (int mi = 0; mi < 4; ++mi)
#pragma unroll
      for (int ni = 0; ni < 4; ++ni)
        acc[mi][ni] = __builtin_amdgcn_mfma_f32_16x16x32_bf16(af[mi], bfr[ni], acc[mi][ni], 0, 0, 0);
    __syncthreads();
  }
  // epilogue: C/D layout col=lane&15, row=quad*4+reg
#pragma unroll
  for (int mi = 0; mi < 4; ++mi) {
#pragma unroll
    for (int ni = 0; ni < 4; ++ni) {
      int col = col0 + wn * 64 + ni * 16 + (lane & 15);
      float bv = bias[col];
#pragma unroll
      for (int r = 0; r < 4; ++r) {
        int row = row0 + wm * 64 + mi * 16 + (lane >> 4) * 4 + r;
        float v = acc[mi][ni][r] + bv;
        if (RELU) v = fmaxf(v, 0.f);
        if (OUT_MODE == 1) {
          unsigned short hi = f2bf(v);
          unsigned short lo = f2bf(v - bf2f(hi));
          ((unsigned short*)C)[(size_t)row * ldc + col] = hi;
          ((unsigned short*)C)[(size_t)row * ldc + col + lo_off] = lo;
        } else {
          if (col < col_lim)
            ((float*)C)[(size_t)row * ldc + col] = v;
        }
      }
    }
  }
}

// ---------------- batchnorm stats (sum, sumsq per channel) ----------------
__global__ __launch_bounds__(256)
void stats_kernel(const float* __restrict__ h2, float* __restrict__ stats) {
  int tid = threadIdx.x;
  int base = blockIdx.x * 128;
  float s0 = 0.f, q0 = 0.f, s1 = 0.f, q1 = 0.f;
  int c1 = tid + 256;
  for (int r = 0; r < 128; ++r) {
    int row = base + r;
    if (row >= N_NODES) break;
    const float* p = h2 + (size_t)row * HS2;
    float v = p[tid];
    s0 += v; q0 += v * v;
    if (c1 < EMB) { float w = p[c1]; s1 += w; q1 += w * w; }
  }
  atomicAdd(&stats[tid], s0);
  atomicAdd(&stats[EMB + tid], q0);
  if (c1 < EMB) { atomicAdd(&stats[c1], s1); atomicAdd(&stats[EMB + c1], q1); }
}

// ---------------- batchnorm apply (+relu), fp16 h out / fp32 final out ----------------
__global__ __launch_bounds__(256)
void bn_kernel(const float* __restrict__ h2, const float* __restrict__ stats,
               const float* __restrict__ gamma, const float* __restrict__ beta,
               __half* __restrict__ hout, float* __restrict__ fout, int relu) {
  int node = blockIdx.x;
  const float invN = 1.0f / (float)N_NODES;
  for (int c = threadIdx.x; c < EMB; c += 256) {
    float mean = stats[c] * invN;
    float var = stats[EMB + c] * invN - mean * mean;
    float scale = gamma[c] * rsqrtf(var + 1e-5f);
    float shift = beta[c] - mean * scale;
    float v = h2[(size_t)node * HS2 + c] * scale + shift;
    if (relu) v = fmaxf(v, 0.f);
    if (hout) hout[(size_t)node * HSH + c] = __float2half(v);
    else      fout[(size_t)node * EMB + c] = v;
  }
}

extern "C" void kernel_launch(void* const* d_in, const int* in_sizes, int n_in,
                              void* d_out, int out_size, void* d_ws, size_t ws_size,
                              hipStream_t stream) {
  const int*   x      = (const int*)d_in[0];
  const int*   ei     = (const int*)d_in[1];
  const int*   ea     = (const int*)d_in[2];
  const float* x_emb1 = (const float*)d_in[3];
  const float* x_emb2 = (const float*)d_in[4];
  const float* edge1  = (const float*)d_in[5];
  const float* edge2  = (const float*)d_in[6];
  const float* W1     = (const float*)d_in[7];
  const float* b1     = (const float*)d_in[8];
  const float* W2     = (const float*)d_in[9];
  const float* b2     = (const float*)d_in[10];
  const float* gamma  = (const float*)d_in[11];
  const float* beta   = (const float*)d_in[12];
  float* out = (float*)d_out;

  char* ws = (char*)d_ws;
  size_t off = 0;
  auto nxt = [&](size_t bytes) {
    void* p = ws + off;
    off += (bytes + 255) & ~(size_t)255;
    return p;
  };
  // Region R: tbuf (bf16 [NPAD][K2D], live gemm1->gemm2) aliases hbuf
  // (fp16 [N_NODES][HSH], read only by aggregate, rewritten by bn).
  size_t tbuf_bytes = (size_t)NPAD * K2D * 2;        // 77.0 MB
  size_t hbuf_bytes = (size_t)N_NODES * HSH * 2;     // 18.2 MB
  char* R = (char*)nxt(tbuf_bytes > hbuf_bytes ? tbuf_bytes : hbuf_bytes);
  __half*         hbuf = (__half*)R;
  unsigned short* tbuf = (unsigned short*)R;
  // Region S: aggb (bf16 [NPAD][K1D], live aggregate->gemm1) aliases h2
  // (fp32 [NPAD][HS2], live gemm2->bn).
  size_t agg_bytes = (size_t)NPAD * K1D * 2;         // 38.5 MB
  size_t h2_bytes  = (size_t)NPAD * HS2 * 4;         // 36.6 MB
  char* S = (char*)nxt(agg_bytes > h2_bytes ? agg_bytes : h2_bytes);
  unsigned short* aggb = (unsigned short*)S;
  float*          h2   = (float*)S;
  unsigned short* w1t  = (unsigned short*)nxt((size_t)LAYERS * NP1 * K1D * 2);
  unsigned short* w2t  = (unsigned short*)nxt((size_t)LAYERS * NP2 * K2D * 2);
  float*          b1p  = (float*)nxt((size_t)LAYERS * NP1 * 4);
  float*          b2p  = (float*)nxt((size_t)LAYERS * NP2 * 4);
  float*          stat = (float*)nxt((size_t)LAYERS * 2 * EMB * 4);
  int*            deg  = (int*)nxt((size_t)N_NODES * 4);
  int*            rptr = (int*)nxt((size_t)(N_NODES + 1) * 4);
  int*            curs = (int*)nxt((size_t)N_NODES * 4);
  int*            ebuf = (int*)nxt((size_t)N_EDGES * 4);
  // total ~125.9 MB

  hipMemsetAsync(deg, 0, (size_t)N_NODES * 4, stream);
  hipMemsetAsync(stat, 0, (size_t)LAYERS * 2 * EMB * 4, stream);

  conv_w1t_kernel<<<(LAYERS * NP1 * K1D + 255) / 256, 256, 0, stream>>>(W1, w1t);
  conv_w2t_kernel<<<(LAYERS * NP2 * K2D + 255) / 256, 256, 0, stream>>>(W2, w2t);
  conv_bias_kernel<<<(LAYERS * NP1 + 255) / 256, 256, 0, stream>>>(b1, b1p, 2 * EMB, NP1);
  conv_bias_kernel<<<(LAYERS * NP2 + 255) / 256, 256, 0, stream>>>(b2, b2p, EMB, NP2);

  embed_kernel<<<N_NODES, 256, 0, stream>>>(x, x_emb1, x_emb2, hbuf);

  count_kernel<<<(N_EDGES + 255) / 256, 256, 0, stream>>>(ei, deg);
  scan_kernel<<<1, 1024, 0, stream>>>(deg, rptr);
  copy_kernel<<<(N_NODES + 255) / 256, 256, 0, stream>>>(rptr, curs);
  fill_kernel<<<(N_EDGES + 255) / 256, 256, 0, stream>>>(ei, ea, curs, ebuf);

  for (int l = 0; l < LAYERS; ++l) {
    aggregate_kernel<<<NPAD / 4, 256, 0, stream>>>(
        hbuf, rptr, ebuf, edge1 + (size_t)l * 6 * EMB, edge2 + (size_t)l * 3 * EMB, aggb);
    gemm_kernel<1, 1><<<dim3(NPAD / 128, NP1 / 128), 256, 0, stream>>>(
        aggb, K1D, w1t + (size_t)l * NP1 * K1D, K1D, b1p + l * NP1, tbuf, K2D, K1D, NP1, NP1);
    gemm_kernel<0, 0><<<dim3(NPAD / 128, NP2 / 128), 256, 0, stream>>>(
        tbuf, K2D, w2t + (size_t)l * NP2 * K2D, K2D, b2p + l * NP2, h2, HS2, K2D, 0, HS2);
    stats_kernel<<<NPAD / 128, 256, 0, stream>>>(h2, stat + l * 2 * EMB);
    bn_kernel<<<N_NODES, 256, 0, stream>>>(
        h2, stat + l * 2 * EMB, gamma + l * EMB, beta + l * EMB,
        (l < LAYERS - 1) ? hbuf : (__half*)nullptr,
        (l < LAYERS - 1) ? (float*)nullptr : out,
        (l < LAYERS - 1) ? 1 : 0);
  }
}

// Round 5
// 1056.347 us; speedup vs baseline: 1.3686x; 1.2731x over previous
//
#include <hip/hip_runtime.h>
#include <hip/hip_fp16.h>

#define N_NODES 30000
#define N_EDGES 240000
#define EMB     300
#define NPAD    30080   // 235 * 128
#define K1      320     // padded EMB (gemm1 K, agg cols, fp16)
#define NP1     640     // padded 2*EMB (gemm1 out cols = gemm2 K)
#define NP2     384     // gemm2 padded col count (compute)
#define HS2     304     // h2 row stride fp32 (stores masked to col<HS2)
#define HSH     304     // h row stride in fp16 elements
#define LAYERS  5

typedef _Float16 half8 __attribute__((ext_vector_type(8)));
typedef __attribute__((ext_vector_type(4))) float floatx4;

// async 16B global->LDS (per-lane gptr, LDS dest = wave-uniform base + lane*16)
__device__ __forceinline__ void gload16(const void* g, void* l) {
  __builtin_amdgcn_global_load_lds(
      (const __attribute__((address_space(1))) unsigned int*)g,
      (__attribute__((address_space(3))) unsigned int*)l, 16, 0, 0);
}

// ---------------- weight conversion / transpose (fp16) ----------------
__global__ void conv_w1t_kernel(const float* __restrict__ W1, __half* __restrict__ w1t) {
  int idx = blockIdx.x * 256 + threadIdx.x;
  if (idx >= LAYERS * NP1 * K1) return;
  int l = idx / (NP1 * K1);
  int rem = idx % (NP1 * K1);
  int n = rem / K1, k = rem % K1;
  float v = (n < 2 * EMB && k < EMB) ? W1[(size_t)l * EMB * 2 * EMB + (size_t)k * 2 * EMB + n] : 0.f;
  w1t[idx] = __float2half(v);
}
__global__ void conv_w2t_kernel(const float* __restrict__ W2, __half* __restrict__ w2t) {
  int idx = blockIdx.x * 256 + threadIdx.x;
  if (idx >= LAYERS * NP2 * NP1) return;
  int l = idx / (NP2 * NP1);
  int rem = idx % (NP2 * NP1);
  int n = rem / NP1, k = rem % NP1;
  float v = (n < EMB && k < 2 * EMB) ? W2[(size_t)l * 2 * EMB * EMB + (size_t)k * EMB + n] : 0.f;
  w2t[idx] = __float2half(v);
}
__global__ void conv_bias_kernel(const float* __restrict__ b, float* __restrict__ bp,
                                 int n_real, int n_pad) {
  int idx = blockIdx.x * 256 + threadIdx.x;
  if (idx >= LAYERS * n_pad) return;
  int l = idx / n_pad, j = idx % n_pad;
  bp[idx] = (j < n_real) ? b[l * n_real + j] : 0.f;
}

// ---------------- initial embedding (fp16 h) ----------------
__global__ __launch_bounds__(256)
void embed_kernel(const int* __restrict__ x, const float* __restrict__ emb1,
                  const float* __restrict__ emb2, __half* __restrict__ h) {
  int node = blockIdx.x;
  int t0 = x[node * 2], t1 = x[node * 2 + 1];
  for (int c = threadIdx.x; c < EMB; c += 256)
    h[(size_t)node * HSH + c] = __float2half(emb1[t0 * EMB + c] + emb2[t1 * EMB + c]);
}

// ---------------- CSR build ----------------
__global__ void count_kernel(const int* __restrict__ ei, int* __restrict__ deg) {
  int e = blockIdx.x * 256 + threadIdx.x;
  if (e < N_EDGES) atomicAdd(&deg[ei[N_EDGES + e]], 1);
}

__global__ __launch_bounds__(1024)
void scan_kernel(const int* __restrict__ deg, int* __restrict__ row_ptr) {
  __shared__ int smem[1024];
  __shared__ int s_running;
  int tid = threadIdx.x;
  if (tid == 0) s_running = 0;
  __syncthreads();
  for (int base = 0; base < N_NODES; base += 1024) {
    int i = base + tid;
    int v = (i < N_NODES) ? deg[i] : 0;
    smem[tid] = v;
    __syncthreads();
    for (int off = 1; off < 1024; off <<= 1) {
      int t = (tid >= off) ? smem[tid - off] : 0;
      __syncthreads();
      smem[tid] += t;
      __syncthreads();
    }
    int incl = smem[tid];
    int run = s_running;
    if (i < N_NODES) row_ptr[i] = run + incl - v;
    __syncthreads();
    if (tid == 1023) s_running = run + smem[1023];
    __syncthreads();
  }
  if (tid == 0) row_ptr[N_NODES] = s_running;
}

__global__ void copy_kernel(const int* __restrict__ src, int* __restrict__ dst) {
  int i = blockIdx.x * 256 + threadIdx.x;
  if (i < N_NODES) dst[i] = src[i];
}

__global__ void fill_kernel(const int* __restrict__ ei, const int* __restrict__ ea,
                            int* __restrict__ cursor, int* __restrict__ ebuf) {
  int e = blockIdx.x * 256 + threadIdx.x;
  if (e >= N_EDGES) return;
  int d = ei[N_EDGES + e];
  int pos = atomicAdd(&cursor[d], 1);
  ebuf[pos] = ei[e] * 32 + (ea[2 * e] * 3 + ea[2 * e + 1]);  // src*32 + combo
}

// ---------------- aggregation: fp16 gather-sum, fp16 output, 2x edge unroll ----------------
// one wave per node; lane covers half2 slots {lane, lane+64, lane+128(<150)}
__global__ __launch_bounds__(256)
void aggregate_kernel(const __half* __restrict__ h,
                      const int* __restrict__ row_ptr,
                      const int* __restrict__ ebuf,
                      const float* __restrict__ e1,   // [6,300] this layer
                      const float* __restrict__ e2,   // [3,300] this layer
                      __half* __restrict__ agg) {
  __shared__ float2 combo[18][150];
  int tid = threadIdx.x;
  for (int idx = tid; idx < 18 * 150; idx += 256) {
    int t = idx / 150, p = idx % 150;
    int a0 = t / 3, a1 = t % 3;
    float2 c;
    c.x = e1[a0 * EMB + 2 * p]     + e2[a1 * EMB + 2 * p];
    c.y = e1[a0 * EMB + 2 * p + 1] + e2[a1 * EMB + 2 * p + 1];
    combo[t][p] = c;
  }
  __syncthreads();
  int wave = tid >> 6, lane = tid & 63;
  int node = blockIdx.x * 4 + wave;
  // accumulator set 0 (even edges) and set 1 (odd edges) — 2x MLP
  float a0x = 0.f, a0y = 0.f, a1x = 0.f, a1y = 0.f, a2x = 0.f, a2y = 0.f;
  float b0x = 0.f, b0y = 0.f, b1x = 0.f, b1y = 0.f, b2x = 0.f, b2y = 0.f;
  int p2 = lane + 128;
  bool has2 = (p2 < 150);
  if (node < N_NODES) {
    int ebeg = row_ptr[node], eend = row_ptr[node + 1];
    int e = ebeg;
    for (; e + 2 <= eend; e += 2) {
      int v0 = ebuf[e], v1 = ebuf[e + 1];
      int s0 = v0 >> 5, t0 = v0 & 31;
      int s1 = v1 >> 5, t1 = v1 & 31;
      const __half2* hp0 = (const __half2*)(h + (size_t)s0 * HSH);
      const __half2* hp1 = (const __half2*)(h + (size_t)s1 * HSH);
      float2 u00 = __half22float2(hp0[lane]);
      float2 u01 = __half22float2(hp0[lane + 64]);
      float2 u10 = __half22float2(hp1[lane]);
      float2 u11 = __half22float2(hp1[lane + 64]);
      float2 c00 = combo[t0][lane];
      float2 c01 = combo[t0][lane + 64];
      float2 c10 = combo[t1][lane];
      float2 c11 = combo[t1][lane + 64];
      a0x += u00.x + c00.x;  a0y += u00.y + c00.y;
      a1x += u01.x + c01.x;  a1y += u01.y + c01.y;
      b0x += u10.x + c10.x;  b0y += u10.y + c10.y;
      b1x += u11.x + c11.x;  b1y += u11.y + c11.y;
      if (has2) {
        float2 u02 = __half22float2(hp0[p2]);
        float2 u12 = __half22float2(hp1[p2]);
        float2 c02 = combo[t0][p2];
        float2 c12 = combo[t1][p2];
        a2x += u02.x + c02.x;  a2y += u02.y + c02.y;
        b2x += u12.x + c12.x;  b2y += u12.y + c12.y;
      }
    }
    for (; e <= eend; ++e) {   // tail edge (if odd count) + self loop
      int s, t;
      if (e < eend) { int v = ebuf[e]; s = v >> 5; t = v & 31; }
      else          { s = node;        t = 4 * 3 + 0; }
      const __half2* hp = (const __half2*)(h + (size_t)s * HSH);
      float2 u0 = __half22float2(hp[lane]);
      float2 u1 = __half22float2(hp[lane + 64]);
      float2 c0 = combo[t][lane];
      float2 c1 = combo[t][lane + 64];
      a0x += u0.x + c0.x;  a0y += u0.y + c0.y;
      a1x += u1.x + c1.x;  a1y += u1.y + c1.y;
      if (has2) {
        float2 u2 = __half22float2(hp[p2]);
        float2 c2 = combo[t][p2];
        a2x += u2.x + c2.x;  a2y += u2.y + c2.y;
      }
    }
  }
  a0x += b0x; a0y += b0y; a1x += b1x; a1y += b1y; a2x += b2x; a2y += b2y;
  __half2* op = (__half2*)(agg + (size_t)node * K1);
  op[lane]      = __floats2half2_rn(a0x, a0y);
  op[lane + 64] = __floats2half2_rn(a1x, a1y);
  if (p2 < 160) op[p2] = has2 ? __floats2half2_rn(a2x, a2y)
                              : __floats2half2_rn(0.f, 0.f);   // zero K-pad cols
}

// ---------------- fp16 MFMA GEMM: C = act(A @ B^T + bias) ----------------
// m97-style: global_load_lds width=16 staging, unpadded LDS (stride 32 fp16).
// A: [Mpad, lda] fp16 row-major. Bt: [Npad, ldb] fp16, Bt[n][k] = B[k][n].
// 128x128 tile, 4 waves of 64x64, K-step 32 via mfma_f32_16x16x32_f16.
// OUT_HALF: 1 = fp16 store; 0 = fp32 store (cols < col_lim).
template<int RELU, int OUT_HALF>
__global__ __launch_bounds__(256, 2)
void gemm_kernel(const __half* __restrict__ A, int lda,
                 const __half* __restrict__ Bt, int ldb,
                 const float* __restrict__ bias,
                 void* __restrict__ C, int ldc, int K, int col_lim) {
  __shared__ _Float16 As[128 * 32];   // unpadded: row = 64 B, lane-order contiguous
  __shared__ _Float16 Bs[128 * 32];
  int tid = threadIdx.x;
  int wave = tid >> 6, lane = tid & 63;
  int wm = wave >> 1, wn = wave & 1;
  int row0 = blockIdx.x * 128, col0 = blockIdx.y * 128;
  // staging: thread t covers (row sr, 16B chunk sc) and (row 64+sr, chunk sc);
  // LDS offset = tid*16 B (wave-uniform base + lane*16 — required by global_load_lds)
  int sr = tid >> 2, sc = (tid & 3) * 8;           // sc in fp16 elems
  const __half* ga0 = A + (size_t)(row0 + sr) * lda + sc;
  const __half* ga1 = A + (size_t)(row0 + 64 + sr) * lda + sc;
  const __half* gb0 = Bt + (size_t)(col0 + sr) * ldb + sc;
  const __half* gb1 = Bt + (size_t)(col0 + 64 + sr) * ldb + sc;
  _Float16* la0 = &As[sr * 32 + sc];
  _Float16* la1 = &As[(64 + sr) * 32 + sc];
  _Float16* lb0 = &Bs[sr * 32 + sc];
  _Float16* lb1 = &Bs[(64 + sr) * 32 + sc];

  floatx4 zero4 = {0.f, 0.f, 0.f, 0.f};
  floatx4 acc[4][4];
#pragma unroll
  for (int i = 0; i < 4; ++i)
#pragma unroll
    for (int j = 0; j < 4; ++j) acc[i][j] = zero4;

  for (int kc = 0; kc < K; kc += 32) {
    gload16(ga0 + kc, la0);
    gload16(ga1 + kc, la1);
    gload16(gb0 + kc, lb0);
    gload16(gb1 + kc, lb1);
    __syncthreads();   // drains vmcnt (global_load_lds) before any LDS read
    half8 af[4], bfr[4];
#pragma unroll
    for (int mi = 0; mi < 4; ++mi)
      af[mi] = *(const half8*)&As[(wm * 64 + mi * 16 + (lane & 15)) * 32 + (lane >> 4) * 8];
#pragma unroll
    for (int ni = 0; ni < 4; ++ni)
      bfr[ni] = *(const half8*)&Bs[(wn * 64 + ni * 16 + (lane & 15)) * 32 + (lane >> 4) * 8];
#pragma unroll
    for (int mi = 0; mi < 4; ++mi)
#pragma unroll
      for (int ni = 0; ni < 4; ++ni)
        acc[mi][ni] = __builtin_amdgcn_mfma_f32_16x16x32_f16(af[mi], bfr[ni], acc[mi][ni], 0, 0, 0);
    __syncthreads();
  }
  // epilogue: C/D layout col=lane&15, row=quad*4+reg
#pragma unroll
  for (int mi = 0; mi < 4; ++mi) {
#pragma unroll
    for (int ni = 0; ni < 4; ++ni) {
      int col = col0 + wn * 64 + ni * 16 + (lane & 15);
      float bv = bias[col];
#pragma unroll
      for (int r = 0; r < 4; ++r) {
        int row = row0 + wm * 64 + mi * 16 + (lane >> 4) * 4 + r;
        float v = acc[mi][ni][r] + bv;
        if (RELU) v = fmaxf(v, 0.f);
        if (OUT_HALF) {
          ((__half*)C)[(size_t)row * ldc + col] = __float2half(v);
        } else {
          if (col < col_lim)
            ((float*)C)[(size_t)row * ldc + col] = v;
        }
      }
    }
  }
}

// ---------------- batchnorm stats (sum, sumsq per channel) ----------------
__global__ __launch_bounds__(256)
void stats_kernel(const float* __restrict__ h2, float* __restrict__ stats) {
  int tid = threadIdx.x;
  int base = blockIdx.x * 128;
  float s0 = 0.f, q0 = 0.f, s1 = 0.f, q1 = 0.f;
  int c1 = tid + 256;
  for (int r = 0; r < 128; ++r) {
    int row = base + r;
    if (row >= N_NODES) break;
    const float* p = h2 + (size_t)row * HS2;
    float v = p[tid];
    s0 += v; q0 += v * v;
    if (c1 < EMB) { float w = p[c1]; s1 += w; q1 += w * w; }
  }
  atomicAdd(&stats[tid], s0);
  atomicAdd(&stats[EMB + tid], q0);
  if (c1 < EMB) { atomicAdd(&stats[c1], s1); atomicAdd(&stats[EMB + c1], q1); }
}

// ---------------- batchnorm apply (+relu), fp16 h out / fp32 final out ----------------
__global__ __launch_bounds__(256)
void bn_kernel(const float* __restrict__ h2, const float* __restrict__ stats,
               const float* __restrict__ gamma, const float* __restrict__ beta,
               __half* __restrict__ hout, float* __restrict__ fout, int relu) {
  int node = blockIdx.x;
  const float invN = 1.0f / (float)N_NODES;
  for (int c = threadIdx.x; c < EMB; c += 256) {
    float mean = stats[c] * invN;
    float var = stats[EMB + c] * invN - mean * mean;
    float scale = gamma[c] * rsqrtf(var + 1e-5f);
    float shift = beta[c] - mean * scale;
    float v = h2[(size_t)node * HS2 + c] * scale + shift;
    if (relu) v = fmaxf(v, 0.f);
    if (hout) hout[(size_t)node * HSH + c] = __float2half(v);
    else      fout[(size_t)node * EMB + c] = v;
  }
}

extern "C" void kernel_launch(void* const* d_in, const int* in_sizes, int n_in,
                              void* d_out, int out_size, void* d_ws, size_t ws_size,
                              hipStream_t stream) {
  const int*   x      = (const int*)d_in[0];
  const int*   ei     = (const int*)d_in[1];
  const int*   ea     = (const int*)d_in[2];
  const float* x_emb1 = (const float*)d_in[3];
  const float* x_emb2 = (const float*)d_in[4];
  const float* edge1  = (const float*)d_in[5];
  const float* edge2  = (const float*)d_in[6];
  const float* W1     = (const float*)d_in[7];
  const float* b1     = (const float*)d_in[8];
  const float* W2     = (const float*)d_in[9];
  const float* b2     = (const float*)d_in[10];
  const float* gamma  = (const float*)d_in[11];
  const float* beta   = (const float*)d_in[12];
  float* out = (float*)d_out;

  char* ws = (char*)d_ws;
  size_t off = 0;
  auto nxt = [&](size_t bytes) {
    void* p = ws + off;
    off += (bytes + 255) & ~(size_t)255;
    return p;
  };
  // Region R: tbuf (fp16 [NPAD][NP1], live gemm1->gemm2) aliases hbuf
  // (fp16 [N_NODES][HSH], read only by aggregate, rewritten by bn).
  size_t tbuf_bytes = (size_t)NPAD * NP1 * 2;        // 38.5 MB
  size_t hbuf_bytes = (size_t)N_NODES * HSH * 2;     // 18.2 MB
  char* R = (char*)nxt(tbuf_bytes > hbuf_bytes ? tbuf_bytes : hbuf_bytes);
  __half* hbuf = (__half*)R;
  __half* tbuf = (__half*)R;
  // Region S: aggb (fp16 [NPAD][K1], live aggregate->gemm1) aliases h2
  // (fp32 [NPAD][HS2], live gemm2->bn).
  size_t agg_bytes = (size_t)NPAD * K1 * 2;          // 19.3 MB
  size_t h2_bytes  = (size_t)NPAD * HS2 * 4;         // 36.6 MB
  char* S = (char*)nxt(agg_bytes > h2_bytes ? agg_bytes : h2_bytes);
  __half* aggb = (__half*)S;
  float*  h2   = (float*)S;
  __half* w1t  = (__half*)nxt((size_t)LAYERS * NP1 * K1 * 2);
  __half* w2t  = (__half*)nxt((size_t)LAYERS * NP2 * NP1 * 2);
  float*  b1p  = (float*)nxt((size_t)LAYERS * NP1 * 4);
  float*  b2p  = (float*)nxt((size_t)LAYERS * NP2 * 4);
  float*  stat = (float*)nxt((size_t)LAYERS * 2 * EMB * 4);
  int*    deg  = (int*)nxt((size_t)N_NODES * 4);
  int*    rptr = (int*)nxt((size_t)(N_NODES + 1) * 4);
  int*    curs = (int*)nxt((size_t)N_NODES * 4);
  int*    ebuf = (int*)nxt((size_t)N_EDGES * 4);
  // total ~82 MB

  hipMemsetAsync(deg, 0, (size_t)N_NODES * 4, stream);
  hipMemsetAsync(stat, 0, (size_t)LAYERS * 2 * EMB * 4, stream);

  conv_w1t_kernel<<<(LAYERS * NP1 * K1 + 255) / 256, 256, 0, stream>>>(W1, w1t);
  conv_w2t_kernel<<<(LAYERS * NP2 * NP1 + 255) / 256, 256, 0, stream>>>(W2, w2t);
  conv_bias_kernel<<<(LAYERS * NP1 + 255) / 256, 256, 0, stream>>>(b1, b1p, 2 * EMB, NP1);
  conv_bias_kernel<<<(LAYERS * NP2 + 255) / 256, 256, 0, stream>>>(b2, b2p, EMB, NP2);

  embed_kernel<<<N_NODES, 256, 0, stream>>>(x, x_emb1, x_emb2, hbuf);

  count_kernel<<<(N_EDGES + 255) / 256, 256, 0, stream>>>(ei, deg);
  scan_kernel<<<1, 1024, 0, stream>>>(deg, rptr);
  copy_kernel<<<(N_NODES + 255) / 256, 256, 0, stream>>>(rptr, curs);
  fill_kernel<<<(N_EDGES + 255) / 256, 256, 0, stream>>>(ei, ea, curs, ebuf);

  for (int l = 0; l < LAYERS; ++l) {
    aggregate_kernel<<<NPAD / 4, 256, 0, stream>>>(
        hbuf, rptr, ebuf, edge1 + (size_t)l * 6 * EMB, edge2 + (size_t)l * 3 * EMB, aggb);
    gemm_kernel<1, 1><<<dim3(NPAD / 128, NP1 / 128), 256, 0, stream>>>(
        aggb, K1, w1t + (size_t)l * NP1 * K1, K1, b1p + l * NP1, tbuf, NP1, K1, NP1);
    gemm_kernel<0, 0><<<dim3(NPAD / 128, NP2 / 128), 256, 0, stream>>>(
        tbuf, NP1, w2t + (size_t)l * NP2 * NP1, NP1, b2p + l * NP2, h2, HS2, NP1, HS2);
    stats_kernel<<<NPAD / 128, 256, 0, stream>>>(h2, stat + l * 2 * EMB);
    bn_kernel<<<N_NODES, 256, 0, stream>>>(
        h2, stat + l * 2 * EMB, gamma + l * EMB, beta + l * EMB,
        (l < LAYERS - 1) ? hbuf : (__half*)nullptr,
        (l < LAYERS - 1) ? (float*)nullptr : out,
        (l < LAYERS - 1) ? 1 : 0);
  }
}

// Round 6
// 836.147 us; speedup vs baseline: 1.7290x; 1.2634x over previous
//
#include <hip/hip_runtime.h>
#include <hip/hip_fp16.h>

#define N_NODES 30000
#define N_EDGES 240000
#define EMB     300
#define NPAD    30080   // 235 * 128
#define K1      320     // padded EMB (gemm1 K, agg cols, fp16)
#define NP1     640     // padded 2*EMB (gemm1 out cols = gemm2 K)
#define NP2     384     // gemm2 padded col count / h2 fp16 row stride
#define HSH     304     // h row stride in fp16 elements
#define LAYERS  5

typedef _Float16 half8 __attribute__((ext_vector_type(8)));
typedef __attribute__((ext_vector_type(4))) float floatx4;

// async 16B global->LDS (per-lane gptr, LDS dest = wave-uniform base + lane*16)
__device__ __forceinline__ void gload16(const void* g, void* l) {
  __builtin_amdgcn_global_load_lds(
      (const __attribute__((address_space(1))) unsigned int*)g,
      (__attribute__((address_space(3))) unsigned int*)l, 16, 0, 0);
}

// ---------------- weight conversion / transpose (fp16) ----------------
__global__ void conv_w1t_kernel(const float* __restrict__ W1, __half* __restrict__ w1t) {
  int idx = blockIdx.x * 256 + threadIdx.x;
  if (idx >= LAYERS * NP1 * K1) return;
  int l = idx / (NP1 * K1);
  int rem = idx % (NP1 * K1);
  int n = rem / K1, k = rem % K1;
  float v = (n < 2 * EMB && k < EMB) ? W1[(size_t)l * EMB * 2 * EMB + (size_t)k * 2 * EMB + n] : 0.f;
  w1t[idx] = __float2half(v);
}
__global__ void conv_w2t_kernel(const float* __restrict__ W2, __half* __restrict__ w2t) {
  int idx = blockIdx.x * 256 + threadIdx.x;
  if (idx >= LAYERS * NP2 * NP1) return;
  int l = idx / (NP2 * NP1);
  int rem = idx % (NP2 * NP1);
  int n = rem / NP1, k = rem % NP1;
  float v = (n < EMB && k < 2 * EMB) ? W2[(size_t)l * 2 * EMB * EMB + (size_t)k * EMB + n] : 0.f;
  w2t[idx] = __float2half(v);
}
__global__ void conv_bias_kernel(const float* __restrict__ b, float* __restrict__ bp,
                                 int n_real, int n_pad) {
  int idx = blockIdx.x * 256 + threadIdx.x;
  if (idx >= LAYERS * n_pad) return;
  int l = idx / n_pad, j = idx % n_pad;
  bp[idx] = (j < n_real) ? b[l * n_real + j] : 0.f;
}

// ---------------- initial embedding (fp16 h) ----------------
__global__ __launch_bounds__(256)
void embed_kernel(const int* __restrict__ x, const float* __restrict__ emb1,
                  const float* __restrict__ emb2, __half* __restrict__ h) {
  int node = blockIdx.x;
  int t0 = x[node * 2], t1 = x[node * 2 + 1];
  for (int c = threadIdx.x; c < EMB; c += 256)
    h[(size_t)node * HSH + c] = __float2half(emb1[t0 * EMB + c] + emb2[t1 * EMB + c]);
}

// ---------------- CSR build ----------------
__global__ void count_kernel(const int* __restrict__ ei, int* __restrict__ deg) {
  int e = blockIdx.x * 256 + threadIdx.x;
  if (e < N_EDGES) atomicAdd(&deg[ei[N_EDGES + e]], 1);
}

// fast scan: thread-chunked serial + wave shuffle scan + 16-wave LDS scan.
// Writes both row_ptr (CSR offsets) and curs (fill cursors).
#define SCH 30   // 1024 * 30 = 30720 >= N_NODES
__global__ __launch_bounds__(1024)
void scan_kernel(const int* __restrict__ deg, int* __restrict__ row_ptr,
                 int* __restrict__ curs) {
  int tid = threadIdx.x;
  int base = tid * SCH;
  int loc[SCH];
  int s = 0;
#pragma unroll
  for (int j = 0; j < SCH; ++j) {
    int i = base + j;
    int v = (i < N_NODES) ? deg[i] : 0;
    loc[j] = s;          // exclusive prefix within chunk
    s += v;
  }
  int lane = tid & 63, wv = tid >> 6;
  int x = s;
#pragma unroll
  for (int o = 1; o < 64; o <<= 1) {
    int y = __shfl_up(x, o, 64);
    if (lane >= o) x += y;
  }
  __shared__ int wsum[16], woff[16];
  if (lane == 63) wsum[wv] = x;
  __syncthreads();
  if (tid == 0) {
    int acc = 0;
    for (int w = 0; w < 16; ++w) { woff[w] = acc; acc += wsum[w]; }
    row_ptr[N_NODES] = acc;
  }
  __syncthreads();
  int excl = woff[wv] + x - s;    // exclusive prefix of this thread's chunk
#pragma unroll
  for (int j = 0; j < SCH; ++j) {
    int i = base + j;
    if (i < N_NODES) { int val = excl + loc[j]; row_ptr[i] = val; curs[i] = val; }
  }
}

__global__ void fill_kernel(const int* __restrict__ ei, const int* __restrict__ ea,
                            int* __restrict__ cursor, int* __restrict__ ebuf) {
  int e = blockIdx.x * 256 + threadIdx.x;
  if (e >= N_EDGES) return;
  int d = ei[N_EDGES + e];
  int pos = atomicAdd(&cursor[d], 1);
  ebuf[pos] = ei[e] * 32 + (ea[2 * e] * 3 + ea[2 * e + 1]);  // src*32 + combo
}

// ---------------- aggregation: fp16 gather-sum, fp16 output, 2x edge unroll ----------------
// one wave per node; lane covers half2 slots {lane, lane+64, lane+128(<150)}
__global__ __launch_bounds__(256)
void aggregate_kernel(const __half* __restrict__ h,
                      const int* __restrict__ row_ptr,
                      const int* __restrict__ ebuf,
                      const float* __restrict__ e1,   // [6,300] this layer
                      const float* __restrict__ e2,   // [3,300] this layer
                      __half* __restrict__ agg) {
  __shared__ __half2 combo[18][150];   // 10.8 KB (was 21.6 fp32) -> 2x block residency
  int tid = threadIdx.x;
  for (int idx = tid; idx < 18 * 150; idx += 256) {
    int t = idx / 150, p = idx % 150;
    int a0 = t / 3, a1 = t % 3;
    combo[t][p] = __floats2half2_rn(e1[a0 * EMB + 2 * p]     + e2[a1 * EMB + 2 * p],
                                    e1[a0 * EMB + 2 * p + 1] + e2[a1 * EMB + 2 * p + 1]);
  }
  __syncthreads();
  int wave = tid >> 6, lane = tid & 63;
  int node = blockIdx.x * 4 + wave;
  float a0x = 0.f, a0y = 0.f, a1x = 0.f, a1y = 0.f, a2x = 0.f, a2y = 0.f;
  float b0x = 0.f, b0y = 0.f, b1x = 0.f, b1y = 0.f, b2x = 0.f, b2y = 0.f;
  int p2 = lane + 128;
  bool has2 = (p2 < 150);
  if (node < N_NODES) {
    int ebeg = row_ptr[node], eend = row_ptr[node + 1];
    int e = ebeg;
    for (; e + 2 <= eend; e += 2) {
      int v0 = ebuf[e], v1 = ebuf[e + 1];
      int s0 = v0 >> 5, t0 = v0 & 31;
      int s1 = v1 >> 5, t1 = v1 & 31;
      const __half2* hp0 = (const __half2*)(h + (size_t)s0 * HSH);
      const __half2* hp1 = (const __half2*)(h + (size_t)s1 * HSH);
      float2 u00 = __half22float2(hp0[lane]);
      float2 u01 = __half22float2(hp0[lane + 64]);
      float2 u10 = __half22float2(hp1[lane]);
      float2 u11 = __half22float2(hp1[lane + 64]);
      float2 c00 = __half22float2(combo[t0][lane]);
      float2 c01 = __half22float2(combo[t0][lane + 64]);
      float2 c10 = __half22float2(combo[t1][lane]);
      float2 c11 = __half22float2(combo[t1][lane + 64]);
      a0x += u00.x + c00.x;  a0y += u00.y + c00.y;
      a1x += u01.x + c01.x;  a1y += u01.y + c01.y;
      b0x += u10.x + c10.x;  b0y += u10.y + c10.y;
      b1x += u11.x + c11.x;  b1y += u11.y + c11.y;
      if (has2) {
        float2 u02 = __half22float2(hp0[p2]);
        float2 u12 = __half22float2(hp1[p2]);
        float2 c02 = __half22float2(combo[t0][p2]);
        float2 c12 = __half22float2(combo[t1][p2]);
        a2x += u02.x + c02.x;  a2y += u02.y + c02.y;
        b2x += u12.x + c12.x;  b2y += u12.y + c12.y;
      }
    }
    for (; e <= eend; ++e) {   // tail edge (if odd count) + self loop
      int s, t;
      if (e < eend) { int v = ebuf[e]; s = v >> 5; t = v & 31; }
      else          { s = node;        t = 4 * 3 + 0; }
      const __half2* hp = (const __half2*)(h + (size_t)s * HSH);
      float2 u0 = __half22float2(hp[lane]);
      float2 u1 = __half22float2(hp[lane + 64]);
      float2 c0 = __half22float2(combo[t][lane]);
      float2 c1 = __half22float2(combo[t][lane + 64]);
      a0x += u0.x + c0.x;  a0y += u0.y + c0.y;
      a1x += u1.x + c1.x;  a1y += u1.y + c1.y;
      if (has2) {
        float2 u2 = __half22float2(hp[p2]);
        float2 c2 = __half22float2(combo[t][p2]);
        a2x += u2.x + c2.x;  a2y += u2.y + c2.y;
      }
    }
  }
  a0x += b0x; a0y += b0y; a1x += b1x; a1y += b1y; a2x += b2x; a2y += b2y;
  __half2* op = (__half2*)(agg + (size_t)node * K1);
  op[lane]      = __floats2half2_rn(a0x, a0y);
  op[lane + 64] = __floats2half2_rn(a1x, a1y);
  if (p2 < 160) op[p2] = has2 ? __floats2half2_rn(a2x, a2y)
                              : __floats2half2_rn(0.f, 0.f);   // zero K-pad cols
}

// ---------------- fp16 MFMA GEMM: C = act(A @ B^T + bias) ----------------
// m97-style: global_load_lds width=16 staging, unpadded LDS (stride 32 fp16).
// 128x128 tile, 4 waves of 64x64, K-step 32 via mfma_f32_16x16x32_f16.
// STATS: fuse BN sum/sumsq accumulation (rows < N_NODES, cols < EMB) into epilogue.
template<int RELU, int STATS>
__global__ __launch_bounds__(256, 2)
void gemm_kernel(const __half* __restrict__ A, int lda,
                 const __half* __restrict__ Bt, int ldb,
                 const float* __restrict__ bias,
                 __half* __restrict__ C, int ldc, int K,
                 float* __restrict__ stats) {
  __shared__ _Float16 As[128 * 32];   // unpadded: row = 64 B, lane-order contiguous
  __shared__ _Float16 Bs[128 * 32];
  __shared__ float cs[128], cq[128];
  int tid = threadIdx.x;
  int wave = tid >> 6, lane = tid & 63;
  int wm = wave >> 1, wn = wave & 1;
  int row0 = blockIdx.x * 128, col0 = blockIdx.y * 128;
  int sr = tid >> 2, sc = (tid & 3) * 8;           // staging row / fp16 col chunk
  const __half* ga0 = A + (size_t)(row0 + sr) * lda + sc;
  const __half* ga1 = A + (size_t)(row0 + 64 + sr) * lda + sc;
  const __half* gb0 = Bt + (size_t)(col0 + sr) * ldb + sc;
  const __half* gb1 = Bt + (size_t)(col0 + 64 + sr) * ldb + sc;
  _Float16* la0 = &As[sr * 32 + sc];
  _Float16* la1 = &As[(64 + sr) * 32 + sc];
  _Float16* lb0 = &Bs[sr * 32 + sc];
  _Float16* lb1 = &Bs[(64 + sr) * 32 + sc];

  if (STATS && tid < 128) { cs[tid] = 0.f; cq[tid] = 0.f; }

  floatx4 zero4 = {0.f, 0.f, 0.f, 0.f};
  floatx4 acc[4][4];
#pragma unroll
  for (int i = 0; i < 4; ++i)
#pragma unroll
    for (int j = 0; j < 4; ++j) acc[i][j] = zero4;

  for (int kc = 0; kc < K; kc += 32) {
    gload16(ga0 + kc, la0);
    gload16(ga1 + kc, la1);
    gload16(gb0 + kc, lb0);
    gload16(gb1 + kc, lb1);
    __syncthreads();   // drains vmcnt (global_load_lds) before any LDS read
    half8 af[4], bfr[4];
#pragma unroll
    for (int mi = 0; mi < 4; ++mi)
      af[mi] = *(const half8*)&As[(wm * 64 + mi * 16 + (lane & 15)) * 32 + (lane >> 4) * 8];
#pragma unroll
    for (int ni = 0; ni < 4; ++ni)
      bfr[ni] = *(const half8*)&Bs[(wn * 64 + ni * 16 + (lane & 15)) * 32 + (lane >> 4) * 8];
#pragma unroll
    for (int mi = 0; mi < 4; ++mi)
#pragma unroll
      for (int ni = 0; ni < 4; ++ni)
        acc[mi][ni] = __builtin_amdgcn_mfma_f32_16x16x32_f16(af[mi], bfr[ni], acc[mi][ni], 0, 0, 0);
    __syncthreads();
  }
  // epilogue: C/D layout col=lane&15, row=quad*4+reg
  float ls[4] = {0.f, 0.f, 0.f, 0.f}, lq[4] = {0.f, 0.f, 0.f, 0.f};
#pragma unroll
  for (int mi = 0; mi < 4; ++mi) {
#pragma unroll
    for (int ni = 0; ni < 4; ++ni) {
      int col = col0 + wn * 64 + ni * 16 + (lane & 15);
      float bv = bias[col];
#pragma unroll
      for (int r = 0; r < 4; ++r) {
        int row = row0 + wm * 64 + mi * 16 + (lane >> 4) * 4 + r;
        float v = acc[mi][ni][r] + bv;
        if (RELU) v = fmaxf(v, 0.f);
        C[(size_t)row * ldc + col] = __float2half(v);
        if (STATS && row < N_NODES) { ls[ni] += v; lq[ni] += v * v; }
      }
    }
  }
  if (STATS) {
#pragma unroll
    for (int ni = 0; ni < 4; ++ni) {
      int ci = wn * 64 + ni * 16 + (lane & 15);
      atomicAdd(&cs[ci], ls[ni]);
      atomicAdd(&cq[ci], lq[ni]);
    }
    __syncthreads();
    int col = col0 + tid;
    if (tid < 128 && col < EMB) {
      atomicAdd(&stats[col], cs[tid]);
      atomicAdd(&stats[EMB + col], cq[tid]);
    }
  }
}

// ---------------- batchnorm apply (+relu), fp16 h2 in, fp16 h out / fp32 final out ----------------
__global__ __launch_bounds__(256)
void bn_kernel(const __half* __restrict__ h2, const float* __restrict__ stats,
               const float* __restrict__ gamma, const float* __restrict__ beta,
               __half* __restrict__ hout, float* __restrict__ fout, int relu) {
  int node = blockIdx.x;
  const float invN = 1.0f / (float)N_NODES;
  for (int c = threadIdx.x; c < EMB; c += 256) {
    float mean = stats[c] * invN;
    float var = stats[EMB + c] * invN - mean * mean;
    float scale = gamma[c] * rsqrtf(var + 1e-5f);
    float shift = beta[c] - mean * scale;
    float v = __half2float(h2[(size_t)node * NP2 + c]) * scale + shift;
    if (relu) v = fmaxf(v, 0.f);
    if (hout) hout[(size_t)node * HSH + c] = __float2half(v);
    else      fout[(size_t)node * EMB + c] = v;
  }
}

extern "C" void kernel_launch(void* const* d_in, const int* in_sizes, int n_in,
                              void* d_out, int out_size, void* d_ws, size_t ws_size,
                              hipStream_t stream) {
  const int*   x      = (const int*)d_in[0];
  const int*   ei     = (const int*)d_in[1];
  const int*   ea     = (const int*)d_in[2];
  const float* x_emb1 = (const float*)d_in[3];
  const float* x_emb2 = (const float*)d_in[4];
  const float* edge1  = (const float*)d_in[5];
  const float* edge2  = (const float*)d_in[6];
  const float* W1     = (const float*)d_in[7];
  const float* b1     = (const float*)d_in[8];
  const float* W2     = (const float*)d_in[9];
  const float* b2     = (const float*)d_in[10];
  const float* gamma  = (const float*)d_in[11];
  const float* beta   = (const float*)d_in[12];
  float* out = (float*)d_out;

  char* ws = (char*)d_ws;
  size_t off = 0;
  auto nxt = [&](size_t bytes) {
    void* p = ws + off;
    off += (bytes + 255) & ~(size_t)255;
    return p;
  };
  // Region R: tbuf (fp16 [NPAD][NP1], live gemm1->gemm2) aliases hbuf
  // (fp16 [N_NODES][HSH], read only by aggregate, rewritten by bn).
  size_t tbuf_bytes = (size_t)NPAD * NP1 * 2;        // 38.5 MB
  size_t hbuf_bytes = (size_t)N_NODES * HSH * 2;     // 18.2 MB
  char* R = (char*)nxt(tbuf_bytes > hbuf_bytes ? tbuf_bytes : hbuf_bytes);
  __half* hbuf = (__half*)R;
  __half* tbuf = (__half*)R;
  // Region S: aggb (fp16 [NPAD][K1], live aggregate->gemm1) aliases h2
  // (fp16 [NPAD][NP2], live gemm2->bn).
  size_t agg_bytes = (size_t)NPAD * K1 * 2;          // 19.3 MB
  size_t h2_bytes  = (size_t)NPAD * NP2 * 2;         // 23.1 MB
  char* S = (char*)nxt(agg_bytes > h2_bytes ? agg_bytes : h2_bytes);
  __half* aggb = (__half*)S;
  __half* h2   = (__half*)S;
  __half* w1t  = (__half*)nxt((size_t)LAYERS * NP1 * K1 * 2);
  __half* w2t  = (__half*)nxt((size_t)LAYERS * NP2 * NP1 * 2);
  float*  b1p  = (float*)nxt((size_t)LAYERS * NP1 * 4);
  float*  b2p  = (float*)nxt((size_t)LAYERS * NP2 * 4);
  float*  stat = (float*)nxt((size_t)LAYERS * 2 * EMB * 4);
  int*    deg  = (int*)nxt((size_t)N_NODES * 4);
  int*    rptr = (int*)nxt((size_t)(N_NODES + 1) * 4);
  int*    curs = (int*)nxt((size_t)N_NODES * 4);
  int*    ebuf = (int*)nxt((size_t)N_EDGES * 4);
  // total ~68 MB

  hipMemsetAsync(deg, 0, (size_t)N_NODES * 4, stream);
  hipMemsetAsync(stat, 0, (size_t)LAYERS * 2 * EMB * 4, stream);

  conv_w1t_kernel<<<(LAYERS * NP1 * K1 + 255) / 256, 256, 0, stream>>>(W1, w1t);
  conv_w2t_kernel<<<(LAYERS * NP2 * NP1 + 255) / 256, 256, 0, stream>>>(W2, w2t);
  conv_bias_kernel<<<(LAYERS * NP1 + 255) / 256, 256, 0, stream>>>(b1, b1p, 2 * EMB, NP1);
  conv_bias_kernel<<<(LAYERS * NP2 + 255) / 256, 256, 0, stream>>>(b2, b2p, EMB, NP2);

  embed_kernel<<<N_NODES, 256, 0, stream>>>(x, x_emb1, x_emb2, hbuf);

  count_kernel<<<(N_EDGES + 255) / 256, 256, 0, stream>>>(ei, deg);
  scan_kernel<<<1, 1024, 0, stream>>>(deg, rptr, curs);
  fill_kernel<<<(N_EDGES + 255) / 256, 256, 0, stream>>>(ei, ea, curs, ebuf);

  for (int l = 0; l < LAYERS; ++l) {
    aggregate_kernel<<<NPAD / 4, 256, 0, stream>>>(
        hbuf, rptr, ebuf, edge1 + (size_t)l * 6 * EMB, edge2 + (size_t)l * 3 * EMB, aggb);
    gemm_kernel<1, 0><<<dim3(NPAD / 128, NP1 / 128), 256, 0, stream>>>(
        aggb, K1, w1t + (size_t)l * NP1 * K1, K1, b1p + l * NP1, tbuf, NP1, K1, nullptr);
    gemm_kernel<0, 1><<<dim3(NPAD / 128, NP2 / 128), 256, 0, stream>>>(
        tbuf, NP1, w2t + (size_t)l * NP2 * NP1, NP1, b2p + l * NP2, h2, NP2, NP1,
        stat + l * 2 * EMB);
    bn_kernel<<<N_NODES, 256, 0, stream>>>(
        h2, stat + l * 2 * EMB, gamma + l * EMB, beta + l * EMB,
        (l < LAYERS - 1) ? hbuf : (__half*)nullptr,
        (l < LAYERS - 1) ? (float*)nullptr : out,
        (l < LAYERS - 1) ? 1 : 0);
  }
}